// Round 1
// baseline (672.710 us; speedup 1.0000x reference)
//
#include <hip/hip_runtime.h>
#include <hip/hip_bf16.h>

#define B_      16
#define CIN_    512
#define COUT_   3
#define WDIM_   512
#define HW_     16384            // 128*128
#define FC_GAIN     0.044194173824159216f   // 1/sqrt(512)
#define WEIGHT_GAIN 0.044194173824159216f   // 1/sqrt(512*1)
#define CLAMP_  256.0f

// Kernel 1: one wave per (b, c). Computes
//   s_j = dot(w[b], affine_W[row_j]) * FC_GAIN + affine_b[row_j],  rows c, c+512, c+1024
//   style = (s1*s2 + s3) * WEIGHT_GAIN
//   eff4[b*512+c] = { conv_w[0][c]*style, conv_w[1][c]*style, conv_w[2][c]*style, 0 }
__global__ __launch_bounds__(64) void style_kernel(
    const float* __restrict__ w,
    const float* __restrict__ affine_W,
    const float* __restrict__ affine_b,
    const float* __restrict__ conv_w,
    float4* __restrict__ eff4) {
  const int bc   = blockIdx.x;        // 0 .. B*CIN-1
  const int b    = bc >> 9;           // / 512
  const int c    = bc & 511;
  const int lane = threadIdx.x;       // 0..63

  const float* wb = w + b * WDIM_;
  const float* r1 = affine_W + (size_t)c * WDIM_;
  const float* r2 = affine_W + (size_t)(c + CIN_) * WDIM_;
  const float* r3 = affine_W + (size_t)(c + 2 * CIN_) * WDIM_;

  float p1 = 0.f, p2 = 0.f, p3 = 0.f;
#pragma unroll
  for (int j = 0; j < WDIM_ / 64; ++j) {
    const int k = j * 64 + lane;      // coalesced across the wave
    const float wk = wb[k];
    p1 = fmaf(wk, r1[k], p1);
    p2 = fmaf(wk, r2[k], p2);
    p3 = fmaf(wk, r3[k], p3);
  }
  // 64-lane butterfly reduce
#pragma unroll
  for (int off = 32; off > 0; off >>= 1) {
    p1 += __shfl_down(p1, off);
    p2 += __shfl_down(p2, off);
    p3 += __shfl_down(p3, off);
  }
  if (lane == 0) {
    const float s1 = p1 * FC_GAIN + affine_b[c];
    const float s2 = p2 * FC_GAIN + affine_b[c + CIN_];
    const float s3 = p3 * FC_GAIN + affine_b[c + 2 * CIN_];
    const float style = (s1 * s2 + s3) * WEIGHT_GAIN;
    float4 e;
    e.x = conv_w[0 * CIN_ + c] * style;
    e.y = conv_w[1 * CIN_ + c] * style;
    e.z = conv_w[2 * CIN_ + c] * style;
    e.w = 0.f;
    eff4[bc] = e;
  }
}

// Kernel 2: out[b,o,h,w] = clamp( sum_c x[b,c,h,w] * eff[b,o,c] + conv_b[o] )
// Grid: 16 batches * 16 pixel-tiles = 256 blocks of 256 threads.
// Each thread owns one float4 (4 pixels), loops over all 512 channels.
__global__ __launch_bounds__(256) void conv_kernel(
    const float* __restrict__ x,
    const float4* __restrict__ eff4,
    const float* __restrict__ conv_b,
    float* __restrict__ out) {
  __shared__ float4 s_eff[CIN_];

  const int b    = blockIdx.x >> 4;   // / 16
  const int tile = blockIdx.x & 15;
  const int tid  = threadIdx.x;

  // stage this batch's effective weights into LDS (8 KB)
  s_eff[tid]       = eff4[b * CIN_ + tid];
  s_eff[tid + 256] = eff4[b * CIN_ + tid + 256];
  __syncthreads();

  // x as float4: (b*CIN + c)*4096 + tile*256 + tid
  const float4* xb = (const float4*)x + ((size_t)b * CIN_) * (HW_ / 4)
                     + (size_t)tile * 256 + tid;

  float a0x = 0.f, a0y = 0.f, a0z = 0.f, a0w = 0.f;
  float a1x = 0.f, a1y = 0.f, a1z = 0.f, a1w = 0.f;
  float a2x = 0.f, a2y = 0.f, a2z = 0.f, a2w = 0.f;

#pragma unroll 8
  for (int c = 0; c < CIN_; ++c) {
    const float4 xv = xb[(size_t)c * (HW_ / 4)];
    const float4 e  = s_eff[c];
    a0x = fmaf(xv.x, e.x, a0x); a0y = fmaf(xv.y, e.x, a0y);
    a0z = fmaf(xv.z, e.x, a0z); a0w = fmaf(xv.w, e.x, a0w);
    a1x = fmaf(xv.x, e.y, a1x); a1y = fmaf(xv.y, e.y, a1y);
    a1z = fmaf(xv.z, e.y, a1z); a1w = fmaf(xv.w, e.y, a1w);
    a2x = fmaf(xv.x, e.z, a2x); a2y = fmaf(xv.y, e.z, a2y);
    a2z = fmaf(xv.z, e.z, a2z); a2w = fmaf(xv.w, e.z, a2w);
  }

  const float b0 = conv_b[0], b1 = conv_b[1], b2 = conv_b[2];
#define CLMP(v, bb) fminf(fmaxf((v) + (bb), -CLAMP_), CLAMP_)
  float4 o0 = make_float4(CLMP(a0x, b0), CLMP(a0y, b0), CLMP(a0z, b0), CLMP(a0w, b0));
  float4 o1 = make_float4(CLMP(a1x, b1), CLMP(a1y, b1), CLMP(a1z, b1), CLMP(a1w, b1));
  float4 o2 = make_float4(CLMP(a2x, b2), CLMP(a2y, b2), CLMP(a2z, b2), CLMP(a2w, b2));
#undef CLMP

  float4* op = (float4*)out + ((size_t)b * COUT_) * (HW_ / 4)
               + (size_t)tile * 256 + tid;
  op[0]                = o0;
  op[1 * (HW_ / 4)]    = o1;
  op[2 * (HW_ / 4)]    = o2;
}

extern "C" void kernel_launch(void* const* d_in, const int* in_sizes, int n_in,
                              void* d_out, int out_size, void* d_ws, size_t ws_size,
                              hipStream_t stream) {
  const float* x        = (const float*)d_in[0];  // [16,512,128,128]
  const float* w        = (const float*)d_in[1];  // [16,512]
  const float* affine_W = (const float*)d_in[2];  // [1536,512]
  const float* affine_b = (const float*)d_in[3];  // [1536]
  const float* conv_w   = (const float*)d_in[4];  // [3,512]
  const float* conv_b   = (const float*)d_in[5];  // [3]
  float* out = (float*)d_out;                     // [16,3,128,128]

  float4* eff4 = (float4*)d_ws;                   // 16*512 float4 = 128 KB

  style_kernel<<<B_ * CIN_, 64, 0, stream>>>(w, affine_W, affine_b, conv_w, eff4);
  conv_kernel<<<B_ * 16, 256, 0, stream>>>(x, eff4, conv_b, out);
}